// Round 4
// baseline (88.359 us; speedup 1.0000x reference)
//
#include <hip/hip_runtime.h>
#include <math.h>

// Contour-to-distance-map, round 4.
// R3 evidence: winding ~35us vs ~18.7us issue floor; 4 transcendentals/iter
// (rsq, sqrt, exp, rcp) serialize the chain. Top-5 dispatches are the
// harness's 268MB 0xAA poison fills (~40us) — not controllable.
// Changes:
//   (a) atan2 formulation: sign*acos(dot/(|a||b|)) == copysign(atan2(|cross|,
//       dot), cross). No norms needed -> rsq and in-acos sqrt gone; one rcp
//       remains. Reference's cos-clip replicated exactly by clamping ang to
//       [acos(1-1e-5), pi-acos(1-1e-5)] (acos is monotone).
//       Dropping the max(norm,eps) floors is safe: floor active => pixel
//       within 1e-5 of a vertex => min_diff<1e-5 => output error <1e-4.
//   (b) wave-skip tanh: tanh(1e5*|cross|)==1.0f exactly when |cross|>=1e-4
//       (99.97% of samples). __any(a<20) guards exp+rcp; ~4% of wave-iters
//       take the (still-exact) slow path.
//   (c) carried state just {dxc,dyc}; min over squared dist, epilogue sqrt.

#define KK    100000.0f
#define INV_2PI 0.15915494309189535f
#define PI_F  3.14159265358979323846f
#define HPI_F 1.57079632679489662f
#define AMIN  4.472139e-3f            // acos(1 - 1e-5)

__device__ __forceinline__ float atan01(float q) {
    // A&S 4.4.49: atan(q), q in [0,1], |err| <= 1e-5
    const float z = q * q;
    float p = fmaf(z,  0.0208351f, -0.0851330f);
    p = fmaf(z, p,  0.1801410f);
    p = fmaf(z, p, -0.3302995f);
    p = fmaf(z, p,  0.9998660f);
    return q * p;
}

struct Chain {
    float dxc, dyc, minn, w;
};

__device__ __forceinline__ void chain_init(Chain& c, float c0x, float c0y,
                                           float px, float py) {
    c.dxc = c0x - px;
    c.dyc = c0y - py;
    c.minn = fmaf(c.dxc, c.dxc, c.dyc * c.dyc);
    c.w = 0.0f;
}

// phase 1: everything except the tanh factor
__device__ __forceinline__ void chain_ang(Chain& c, float cnx, float cny,
                                          float px, float py,
                                          float& ang, float& cross, float& a) {
    const float dxn = cnx - px;
    const float dyn = cny - py;
    const float d2n = fmaf(dxn, dxn, dyn * dyn);
    c.minn = fminf(c.minn, d2n);

    const float dot = fmaf(c.dxc, dxn, c.dyc * dyn);
    cross = fmaf(c.dyc, dxn, -(c.dxc * dyn));   // dyc*dxn - dxc*dyn

    const float ay = fabsf(cross);
    const float ax = fabsf(dot);
    const float mn = fminf(ax, ay);
    const float mx = fmaxf(ax, ay);
    const float q  = mn * __builtin_amdgcn_rcpf(fmaxf(mx, 1e-30f));
    float an = atan01(q);
    an = (ay > ax)    ? (HPI_F - an) : an;      // octant fixup
    an = (dot < 0.0f) ? (PI_F - an)  : an;      // quadrant fixup
    ang = fminf(fmaxf(an, AMIN), PI_F - AMIN);  // == reference cos-clip

    a = (2.0f * KK) * ay;                       // tanh arg *2
    c.dxc = dxn; c.dyc = dyn;
}

__device__ __forceinline__ float tanh_slow(float a) {
    // exact for all a: (1-e)/(1+e), e=exp(-a); ==1.0f for a>=20
    const float e = __expf(-a);
    return (1.0f - e) * __builtin_amdgcn_rcpf(1.0f + e);
}

__global__ void __launch_bounds__(256)
winding_kernel(const float2* __restrict__ contour, int N, int S, float invS,
               float* __restrict__ out, float* __restrict__ bmax) {
    __shared__ float2 sc[257];           // N+1 <= 257, sc[N] = sc[0] sentinel
    __shared__ float s_w[4][128];
    __shared__ float s_m[4][128];

    const int tid  = threadIdx.x;
    const int lane = tid & 63;
    const int wid  = tid >> 6;

    for (int t = tid; t < N; t += 256) sc[t] = contour[t];
    if (tid == 0) sc[N] = contour[0];
    __syncthreads();

    const int total = S * S;
    const int p0 = blockIdx.x * 128 + lane;   // 128 pixels/block, 2 per lane
    const int p1 = p0 + 64;
    const bool v0 = (p0 < total);
    const bool v1 = (p1 < total);

    const int i0 = p0 / S, j0 = p0 - i0 * S;
    const int i1 = p1 / S, j1 = p1 - i1 * S;
    const float px0 = (float)i0 * invS, py0 = (float)j0 * invS;
    const float px1 = (float)i1 * invS, py1 = (float)j1 * invS;

    // this wave's vertex range [n0, n1)
    const int Q  = (N + 3) >> 2;
    const int n0 = wid * Q;
    const int n1 = (n0 + Q < N) ? (n0 + Q) : N;

    Chain c0, c1;
    chain_init(c0, sc[n0].x, sc[n0].y, px0, py0);
    chain_init(c1, sc[n0].x, sc[n0].y, px1, py1);

    #pragma unroll 5
    for (int n = n0; n < n1; ++n) {
        const float2 cn = sc[n + 1];          // sentinel handles wrap
        float ang0, cr0, a0, ang1, cr1, a1;
        chain_ang(c0, cn.x, cn.y, px0, py0, ang0, cr0, a0);
        chain_ang(c1, cn.x, cn.y, px1, py1, ang1, cr1, a1);

        float t0 = 1.0f, t1 = 1.0f;
        if (__any((a0 < 20.0f) || (a1 < 20.0f))) {   // ~4% of wave-iters
            t0 = tanh_slow(a0);
            t1 = tanh_slow(a1);
        }
        c0.w = fmaf(t0, copysignf(ang0, cr0), c0.w);
        c1.w = fmaf(t1, copysignf(ang1, cr1), c1.w);
    }

    s_w[wid][lane]      = c0.w;
    s_w[wid][lane + 64] = c1.w;
    s_m[wid][lane]      = c0.minn;
    s_m[wid][lane + 64] = c1.minn;
    __syncthreads();

    if (wid < 2) {
        const int idx = wid * 64 + lane;      // entry -> pixel blockIdx*128+idx
        const int pix = blockIdx.x * 128 + idx;
        const bool valid = (wid == 0) ? v0 : v1;

        const float wt = (s_w[0][idx] + s_w[1][idx]) +
                         (s_w[2][idx] + s_w[3][idx]);
        const float mt = fminf(fminf(s_m[0][idx], s_m[1][idx]),
                               fminf(s_m[2][idx], s_m[3][idx]));
        float prod = valid ? (wt * INV_2PI) * __builtin_amdgcn_sqrtf(mt)
                           : -INFINITY;
        if (valid) out[pix] = prod;

        float v = prod;
        #pragma unroll
        for (int off = 32; off >= 1; off >>= 1)
            v = fmaxf(v, __shfl_down(v, off, 64));
        if (lane == 0) bmax[blockIdx.x * 2 + wid] = v;
    }
}

__global__ void __launch_bounds__(256)
normalize_kernel(float4* __restrict__ out4, const float* __restrict__ bmax,
                 int nmax, int total4) {
    const int tid  = threadIdx.x;
    const int lane = tid & 63;
    const int wid  = tid >> 6;

    float m = -INFINITY;
    for (int t = tid; t < nmax; t += 256) m = fmaxf(m, bmax[t]);
    #pragma unroll
    for (int off = 32; off >= 1; off >>= 1)
        m = fmaxf(m, __shfl_down(m, off, 64));
    __shared__ float sm[4];
    if (lane == 0) sm[wid] = m;
    __syncthreads();
    m = fmaxf(fmaxf(sm[0], sm[1]), fmaxf(sm[2], sm[3]));
    const float inv = 1.0f / m;

    const int idx = blockIdx.x * 256 + tid;
    if (idx < total4) {
        float4 v = out4[idx];
        v.x *= inv; v.y *= inv; v.z *= inv; v.w *= inv;
        out4[idx] = v;
    }
}

extern "C" void kernel_launch(void* const* d_in, const int* in_sizes, int n_in,
                              void* d_out, int out_size, void* d_ws, size_t ws_size,
                              hipStream_t stream) {
    const float2* contour = (const float2*)d_in[0];
    const int N = in_sizes[0] / 2;                       // 200
    const int S = (int)(sqrt((double)out_size) + 0.5);   // 384
    const float invS = 1.0f / (float)S;
    float* out  = (float*)d_out;
    float* bmax = (float*)d_ws;

    const int total   = S * S;
    const int wblocks = (total + 127) / 128;             // 1152
    winding_kernel<<<wblocks, 256, 0, stream>>>(contour, N, S, invS, out, bmax);

    const int total4  = total / 4;
    const int nblocks = (total4 + 255) / 256;            // 144
    normalize_kernel<<<nblocks, 256, 0, stream>>>((float4*)out, bmax,
                                                  wblocks * 2, total4);
}